// Round 17
// baseline (35.770 us; speedup 1.0000x reference)
//
#include <hip/hip_runtime.h>
#include <math.h>

// DCNv2 forward: B=4, Cin=Cout=64, H=W=128, 3x3, stride=1, pad=1, dil=1, groups=dg=1
// Round-9 structure + waves_per_eu(4,4) + explicit DEPTH-2 tap pipeline:
//   iter k: [issue tap k+1 ds_reads + weights] -> [MFMA tap k] -> [blend tap k+1]
// so LDS latency hides under the MFMA cluster instead of serializing.
#define H_    128
#define W_    128
#define HW_   (H_ * W_)
#define CIN_  64
#define COUT_ 64
#define K2_   9
#define B_    4
#define NROWS 10
#define LDS_BYTES (NROWS * 128 * 128)   // 163840 (160 KiB)

typedef __bf16 bf16x8 __attribute__((ext_vector_type(8)));
typedef __bf16 bf16x4 __attribute__((ext_vector_type(4)));
typedef float  f32x4  __attribute__((ext_vector_type(4)));

// weight [Cout][Cin][3][3] -> lane-linear MFMA A-frag layout:
// wt3[k][s][ct][lane][e] = weight[ct*16+(lane&15)][s*32+(lane>>4)*8+e][k]
__global__ __launch_bounds__(256) void wtrans3_kernel(const float* __restrict__ w,
                                                      __bf16* __restrict__ wt3) {
    int idx = blockIdx.x * 256 + threadIdx.x;     // 36864
    if (idx >= K2_ * 2 * 4 * 64 * 8) return;
    int e    = idx & 7;
    int lane = (idx >> 3) & 63;
    int ct   = (idx >> 9) & 3;
    int s    = (idx >> 11) & 1;
    int k    = idx >> 12;
    int co   = ct * 16 + (lane & 15);
    int cin  = s * 32 + (lane >> 4) * 8 + e;
    wt3[idx] = (__bf16)w[(co * CIN_ + cin) * K2_ + k];
}

__global__ __launch_bounds__(1024, 4)
__attribute__((amdgpu_waves_per_eu(4, 4)))
void dcn_lds_kernel(
    const float* __restrict__ x,       // [B, Cin, H, W] fp32
    const float* __restrict__ offset,  // [B, 18, H, W]
    const float* __restrict__ mask,    // [B, 9, H, W]
    const __bf16* __restrict__ wt3,    // lane-linear A-frags
    const float* __restrict__ bias,
    float* __restrict__ out)           // [B, Cout, H, W]
{
    extern __shared__ char sm[];

    const int tid  = threadIdx.x;
    const int wave = tid >> 6;
    const int lane = tid & 63;
    const int n16  = lane & 15;
    const int kb   = lane >> 4;

    const int bid0 = blockIdx.x;                    // 256 blocks
    const int bidx = (bid0 & 7) * 32 + (bid0 >> 3); // bijective XCD swizzle
    const int b   = bidx >> 6;
    const int ho0 = (bidx & 63) * 2;                // base output row (even)

    const float* xb = x + (size_t)b * CIN_ * HW_;

    // ---------- stage rows [ho0-4, ho0+5] into swizzled bf16 LDS ----------
    {
        const int g5     = tid >> 5;
        const int px4    = tid & 31;
        const int rowpar = g5 >> 4;
        const int c0     = (g5 & 15) * 4;
        const int chunk  = c0 >> 3;
        const int eoff   = (c0 & 7) * 2;
#pragma unroll
        for (int it = 0; it < 5; ++it) {
            const int r = it * 2 + rowpar;            // 0..9
            const int srow = min(max(ho0 - 4 + r, 0), H_ - 1);
            const float* g = xb + ((size_t)c0 * H_ + srow) * W_ + px4 * 4;
            const float4 v0 = *(const float4*)(g);
            const float4 v1 = *(const float4*)(g + HW_);
            const float4 v2 = *(const float4*)(g + 2 * HW_);
            const float4 v3 = *(const float4*)(g + 3 * HW_);
            const float* f0 = (const float*)&v0;
            const float* f1 = (const float*)&v1;
            const float* f2 = (const float*)&v2;
            const float* f3 = (const float*)&v3;
#pragma unroll
            for (int e = 0; e < 4; ++e) {
                const int px = px4 * 4 + e;
                const int q  = (chunk + px + (px >> 3)) & 7;
                bf16x4 pk;
                pk[0] = (__bf16)f0[e];
                pk[1] = (__bf16)f1[e];
                pk[2] = (__bf16)f2[e];
                pk[3] = (__bf16)f3[e];
                *(bf16x4*)(sm + (((size_t)r * 128 + px) * 8 + q) * 16 + eoff) = pk;
            }
        }
    }
    __syncthreads();

    // ---------- fused sample + MFMA (depth-2 pipeline) ----------
    const int rr  = wave >> 3;
    const int til = wave & 7;
    const int ho  = ho0 + rr;
    const int wos = til * 16 + n16;
    const int pix = ho * W_ + wos;
    const float* offb = offset + (size_t)b * (2 * K2_) * HW_ + pix;
    const float* mb   = mask   + (size_t)b * K2_ * HW_ + pix;

    f32x4 acc[4];
#pragma unroll
    for (int t = 0; t < 4; ++t) acc[t] = (f32x4){0.f, 0.f, 0.f, 0.f};

    // sample stage 1: addresses + ds_reads + weights (+rare fallback) for tap k
    auto sample_corners = [&](int k, float oy_, float ox_, float mm_,
                              bf16x8& a00, bf16x8& c00, bf16x8& a01, bf16x8& c01,
                              bf16x8& a10, bf16x8& c10, bf16x8& a11, bf16x8& c11,
                              float& W00, float& W01, float& W10, float& W11) {
        const int ky = k / 3, kx = k % 3;
        const float py  = (float)(ho - 1 + ky) + oy_;
        const float pxf = (float)(wos - 1 + kx) + ox_;
        const float fy = floorf(py), fx = floorf(pxf);
        const int   y0 = (int)fy,    x0 = (int)fx;
        const float ly = py - fy,    lx = pxf - fx;

        const float vy0 = (y0 >= 0 && y0 < H_)         ? 1.f : 0.f;
        const float vy1 = (y0 + 1 >= 0 && y0 + 1 < H_) ? 1.f : 0.f;
        const float vx0 = (x0 >= 0 && x0 < W_)         ? 1.f : 0.f;
        const float vx1 = (x0 + 1 >= 0 && x0 + 1 < W_) ? 1.f : 0.f;
        W00 = mm_ * (1.f - ly) * (1.f - lx) * vy0 * vx0;
        W01 = mm_ * (1.f - ly) * lx         * vy0 * vx1;
        W10 = mm_ * ly * (1.f - lx)         * vy1 * vx0;
        W11 = mm_ * ly * lx                 * vy1 * vx1;
        const int cy0 = min(max(y0, 0), H_ - 1);
        const int cy1 = min(max(y0 + 1, 0), H_ - 1);
        const int cx0 = min(max(x0, 0), W_ - 1);
        const int cx1 = min(max(x0 + 1, 0), W_ - 1);

        const int s0 = cy0 - ho0 + 4;
        const int s1 = cy1 - ho0 + 4;
        const bool need0 = ((unsigned)s0 > 9u) && (vy0 != 0.f);
        const bool need1 = ((unsigned)s1 > 9u) && (vy1 != 0.f);
        const int s0c = min(max(s0, 0), 9);
        const int s1c = min(max(s1, 0), 9);
        const int key0 = cx0 + (cx0 >> 3);
        const int key1 = cx1 + (cx1 >> 3);

        const char* r00 = sm + ((size_t)(s0c * 128 + cx0) * 8) * 16;
        const char* r01 = sm + ((size_t)(s0c * 128 + cx1) * 8) * 16;
        const char* r10 = sm + ((size_t)(s1c * 128 + cx0) * 8) * 16;
        const char* r11 = sm + ((size_t)(s1c * 128 + cx1) * 8) * 16;

        a00 = *(const bf16x8*)(r00 + (((kb     + key0) & 7) << 4));
        c00 = *(const bf16x8*)(r00 + (((kb + 4 + key0) & 7) << 4));
        a01 = *(const bf16x8*)(r01 + (((kb     + key1) & 7) << 4));
        c01 = *(const bf16x8*)(r01 + (((kb + 4 + key1) & 7) << 4));
        a10 = *(const bf16x8*)(r10 + (((kb     + key0) & 7) << 4));
        c10 = *(const bf16x8*)(r10 + (((kb + 4 + key0) & 7) << 4));
        a11 = *(const bf16x8*)(r11 + (((kb     + key1) & 7) << 4));
        c11 = *(const bf16x8*)(r11 + (((kb + 4 + key1) & 7) << 4));

        if (__builtin_expect(need0, 0)) {
            const float* gl = xb + (size_t)(kb * 8) * HW_ + (size_t)cy0 * W_;
            const float* gh = gl + (size_t)32 * HW_;
#pragma unroll
            for (int e = 0; e < 8; ++e) {
                a00[e] = (__bf16)gl[(size_t)e * HW_ + cx0];
                a01[e] = (__bf16)gl[(size_t)e * HW_ + cx1];
                c00[e] = (__bf16)gh[(size_t)e * HW_ + cx0];
                c01[e] = (__bf16)gh[(size_t)e * HW_ + cx1];
            }
        }
        if (__builtin_expect(need1, 0)) {
            const float* gl = xb + (size_t)(kb * 8) * HW_ + (size_t)cy1 * W_;
            const float* gh = gl + (size_t)32 * HW_;
#pragma unroll
            for (int e = 0; e < 8; ++e) {
                a10[e] = (__bf16)gl[(size_t)e * HW_ + cx0];
                a11[e] = (__bf16)gl[(size_t)e * HW_ + cx1];
                c10[e] = (__bf16)gh[(size_t)e * HW_ + cx0];
                c11[e] = (__bf16)gh[(size_t)e * HW_ + cx1];
            }
        }
    };

    float oy = offb[0];
    float ox = offb[HW_];
    float mm = mb[0];

    // ---- prologue: sample + blend tap 0 ----
    bf16x8 bf0, bf1;
    {
        bf16x8 a00, c00, a01, c01, a10, c10, a11, c11;
        float W00, W01, W10, W11;
        sample_corners(0, oy, ox, mm, a00, c00, a01, c01, a10, c10, a11, c11,
                       W00, W01, W10, W11);
#pragma unroll
        for (int e = 0; e < 8; ++e) {
            bf0[e] = (__bf16)(W00 * (float)a00[e] + W01 * (float)a01[e]
                            + W10 * (float)a10[e] + W11 * (float)a11[e]);
            bf1[e] = (__bf16)(W00 * (float)c00[e] + W01 * (float)c01[e]
                            + W10 * (float)c10[e] + W11 * (float)c11[e]);
        }
    }
    // offsets for tap 1
    oy = offb[2 * HW_];
    ox = offb[3 * HW_];
    mm = mb[HW_];

#pragma unroll
    for (int k = 0; k < K2_; ++k) {
        // ---- stage 1: issue tap k+1's ds_reads + weights ----
        bf16x8 a00, c00, a01, c01, a10, c10, a11, c11;
        float W00 = 0.f, W01 = 0.f, W10 = 0.f, W11 = 0.f;
        if (k + 1 < K2_) {
            sample_corners(k + 1, oy, ox, mm, a00, c00, a01, c01, a10, c10, a11, c11,
                           W00, W01, W10, W11);
        }
        // prefetch offsets for tap k+2
        if (k + 2 < K2_) {
            oy = offb[(2 * (k + 2)) * HW_];
            ox = offb[(2 * (k + 2) + 1) * HW_];
            mm = mb[(k + 2) * HW_];
        }

        // ---- stage 2: MFMA tap k from already-blended bf0/bf1 ----
        const __bf16* wk = wt3 + (size_t)k * (2 * 4 * 64 * 8);
#pragma unroll
        for (int ct = 0; ct < 4; ++ct) {
            const bf16x8 A0 = *(const bf16x8*)(wk + (0 * 4 + ct) * 512 + lane * 8);
            const bf16x8 A1 = *(const bf16x8*)(wk + (1 * 4 + ct) * 512 + lane * 8);
            acc[ct] = __builtin_amdgcn_mfma_f32_16x16x32_bf16(A0, bf0, acc[ct], 0, 0, 0);
            acc[ct] = __builtin_amdgcn_mfma_f32_16x16x32_bf16(A1, bf1, acc[ct], 0, 0, 0);
        }

        // ---- stage 3: blend tap k+1 -> bf0/bf1 ----
        if (k + 1 < K2_) {
#pragma unroll
            for (int e = 0; e < 8; ++e) {
                bf0[e] = (__bf16)(W00 * (float)a00[e] + W01 * (float)a01[e]
                                + W10 * (float)a10[e] + W11 * (float)a11[e]);
                bf1[e] = (__bf16)(W00 * (float)c00[e] + W01 * (float)c01[e]
                                + W10 * (float)c10[e] + W11 * (float)c11[e]);
            }
        }
    }

    // ---------- epilogue: D col = n16 (px), row = kb*4 + r (+ ct*16) ----------
#pragma unroll
    for (int ct = 0; ct < 4; ++ct) {
#pragma unroll
        for (int r = 0; r < 4; ++r) {
            const int co = ct * 16 + kb * 4 + r;
            out[((size_t)(b * COUT_ + co)) * HW_ + pix] = acc[ct][r] + bias[co];
        }
    }
}

extern "C" void kernel_launch(void* const* d_in, const int* in_sizes, int n_in,
                              void* d_out, int out_size, void* d_ws, size_t ws_size,
                              hipStream_t stream) {
    const float* x      = (const float*)d_in[0];
    const float* offset = (const float*)d_in[1];
    const float* mask   = (const float*)d_in[2];
    const float* weight = (const float*)d_in[3];
    const float* bias   = (const float*)d_in[4];
    float* out = (float*)d_out;
    __bf16* wt3 = (__bf16*)d_ws;   // 73728 bytes

    hipFuncSetAttribute(reinterpret_cast<const void*>(dcn_lds_kernel),
                        hipFuncAttributeMaxDynamicSharedMemorySize, LDS_BYTES);

    wtrans3_kernel<<<(K2_ * 2 * 4 * 64 * 8 + 255) / 256, 256, 0, stream>>>(weight, wt3);
    // 256 blocks x 1024 threads: one block per CU, 2 output rows per block
    dcn_lds_kernel<<<B_ * H_ / 2, 1024, LDS_BYTES, stream>>>(x, offset, mask, wt3, bias, out);
}

// Round 18
// 32.655 us; speedup vs baseline: 1.0954x; 1.0954x over previous
//
#include <hip/hip_runtime.h>
#include <math.h>

// DCNv2 forward: B=4, Cin=Cout=64, H=W=128, 3x3, stride=1, pad=1, dil=1, groups=dg=1
// FINAL (round-16): best measured 32.77 us total, absmax 0.0078.
// Structure: one 1024-thread block per CU computes 2 output rows; a 10-row
// bf16 window of x lives in 160 KiB LDS (chunk-swizzled, q=(j+px+(px>>3))&7);
// each lane bilinear-blends its pixel's 16 channels straight into MFMA
// B-fragment layout; 8 mfma_f32_16x16x32_bf16 per tap accumulate all 64 Cout.
// amdgpu_waves_per_eu(4,4) matches the register budget to the true occupancy
// (160 KiB LDS -> 1 block/CU -> 4 waves/SIMD).
// Rare out-of-window samples fall back to exec-masked global reads.
#define H_    128
#define W_    128
#define HW_   (H_ * W_)
#define CIN_  64
#define COUT_ 64
#define K2_   9
#define B_    4
#define NROWS 10
#define LDS_BYTES (NROWS * 128 * 128)   // 10 rows x 128 px x 8 chunks x 16B = 163840 (160 KiB)

typedef __bf16 bf16x8 __attribute__((ext_vector_type(8)));
typedef __bf16 bf16x4 __attribute__((ext_vector_type(4)));
typedef float  f32x4  __attribute__((ext_vector_type(4)));

// weight [Cout][Cin][3][3] -> lane-linear MFMA A-frag layout:
// wt3[k][s][ct][lane][e] = weight[ct*16+(lane&15)][s*32+(lane>>4)*8+e][k]
__global__ __launch_bounds__(256) void wtrans3_kernel(const float* __restrict__ w,
                                                      __bf16* __restrict__ wt3) {
    int idx = blockIdx.x * 256 + threadIdx.x;     // 9*2*4*64*8 = 36864
    if (idx >= K2_ * 2 * 4 * 64 * 8) return;
    int e    = idx & 7;
    int lane = (idx >> 3) & 63;
    int ct   = (idx >> 9) & 3;
    int s    = (idx >> 11) & 1;
    int k    = idx >> 12;
    int co   = ct * 16 + (lane & 15);
    int cin  = s * 32 + (lane >> 4) * 8 + e;
    wt3[idx] = (__bf16)w[(co * CIN_ + cin) * K2_ + k];
}

// One block = 2 output rows (256 px), 1024 thr = 16 waves x 16-px tiles
// (wave>>3 selects the row, wave&7 the 16-px tile).
__global__ __launch_bounds__(1024, 4)
__attribute__((amdgpu_waves_per_eu(4, 4)))
void dcn_lds_kernel(
    const float* __restrict__ x,       // [B, Cin, H, W] fp32
    const float* __restrict__ offset,  // [B, 18, H, W]
    const float* __restrict__ mask,    // [B, 9, H, W]
    const __bf16* __restrict__ wt3,    // lane-linear A-frags
    const float* __restrict__ bias,
    float* __restrict__ out)           // [B, Cout, H, W]
{
    extern __shared__ char sm[];

    const int tid  = threadIdx.x;
    const int wave = tid >> 6;
    const int lane = tid & 63;
    const int n16  = lane & 15;
    const int kb   = lane >> 4;

    const int bid0 = blockIdx.x;                    // 256 blocks
    const int bidx = (bid0 & 7) * 32 + (bid0 >> 3); // bijective XCD swizzle
    const int b   = bidx >> 6;
    const int ho0 = (bidx & 63) * 2;                // base output row (even)

    const float* xb = x + (size_t)b * CIN_ * HW_;

    // ---------- stage rows [ho0-4, ho0+5] into swizzled bf16 LDS ----------
    {
        const int g5     = tid >> 5;      // 0..31
        const int px4    = tid & 31;      // 4-px granule
        const int rowpar = g5 >> 4;       // row parity 0/1
        const int c0     = (g5 & 15) * 4; // channel group of 4
        const int chunk  = c0 >> 3;
        const int eoff   = (c0 & 7) * 2;  // byte offset within chunk (0 or 8)
#pragma unroll
        for (int it = 0; it < 5; ++it) {
            const int r = it * 2 + rowpar;            // 0..9
            const int srow = min(max(ho0 - 4 + r, 0), H_ - 1);
            const float* g = xb + ((size_t)c0 * H_ + srow) * W_ + px4 * 4;
            const float4 v0 = *(const float4*)(g);
            const float4 v1 = *(const float4*)(g + HW_);
            const float4 v2 = *(const float4*)(g + 2 * HW_);
            const float4 v3 = *(const float4*)(g + 3 * HW_);
            const float* f0 = (const float*)&v0;
            const float* f1 = (const float*)&v1;
            const float* f2 = (const float*)&v2;
            const float* f3 = (const float*)&v3;
#pragma unroll
            for (int e = 0; e < 4; ++e) {
                const int px = px4 * 4 + e;
                const int q  = (chunk + px + (px >> 3)) & 7;
                bf16x4 pk;
                pk[0] = (__bf16)f0[e];
                pk[1] = (__bf16)f1[e];
                pk[2] = (__bf16)f2[e];
                pk[3] = (__bf16)f3[e];
                *(bf16x4*)(sm + (((size_t)r * 128 + px) * 8 + q) * 16 + eoff) = pk;
            }
        }
    }
    __syncthreads();

    // ---------- fused sample + MFMA ----------
    const int rr  = wave >> 3;            // which of the 2 output rows
    const int til = wave & 7;             // 16-px tile within the row
    const int ho  = ho0 + rr;
    const int wos = til * 16 + n16;
    const int pix = ho * W_ + wos;
    const float* offb = offset + (size_t)b * (2 * K2_) * HW_ + pix;
    const float* mb   = mask   + (size_t)b * K2_ * HW_ + pix;

    f32x4 acc[4];
#pragma unroll
    for (int t = 0; t < 4; ++t) acc[t] = (f32x4){0.f, 0.f, 0.f, 0.f};

    float oy = offb[0];
    float ox = offb[HW_];
    float mm = mb[0];

#pragma unroll 3
    for (int k = 0; k < K2_; ++k) {
        const int ky = k / 3, kx = k % 3;
        const float py  = (float)(ho - 1 + ky) + oy;
        const float pxf = (float)(wos - 1 + kx) + ox;
        const float fy = floorf(py), fx = floorf(pxf);
        const int   y0 = (int)fy,    x0 = (int)fx;
        const float ly = py - fy,    lx = pxf - fx;

        const float vy0 = (y0 >= 0 && y0 < H_)         ? 1.f : 0.f;
        const float vy1 = (y0 + 1 >= 0 && y0 + 1 < H_) ? 1.f : 0.f;
        const float vx0 = (x0 >= 0 && x0 < W_)         ? 1.f : 0.f;
        const float vx1 = (x0 + 1 >= 0 && x0 + 1 < W_) ? 1.f : 0.f;
        const float W00 = mm * (1.f - ly) * (1.f - lx) * vy0 * vx0;
        const float W01 = mm * (1.f - ly) * lx         * vy0 * vx1;
        const float W10 = mm * ly * (1.f - lx)         * vy1 * vx0;
        const float W11 = mm * ly * lx                 * vy1 * vx1;
        const int cy0 = min(max(y0, 0), H_ - 1);
        const int cy1 = min(max(y0 + 1, 0), H_ - 1);
        const int cx0 = min(max(x0, 0), W_ - 1);
        const int cx1 = min(max(x0 + 1, 0), W_ - 1);

        const int s0 = cy0 - ho0 + 4;               // window slot 0..9
        const int s1 = cy1 - ho0 + 4;
        const bool need0 = ((unsigned)s0 > 9u) && (vy0 != 0.f);
        const bool need1 = ((unsigned)s1 > 9u) && (vy1 != 0.f);
        const int s0c = min(max(s0, 0), 9);
        const int s1c = min(max(s1, 0), 9);
        const int key0 = cx0 + (cx0 >> 3);
        const int key1 = cx1 + (cx1 >> 3);

        const char* r00 = sm + ((size_t)(s0c * 128 + cx0) * 8) * 16;
        const char* r01 = sm + ((size_t)(s0c * 128 + cx1) * 8) * 16;
        const char* r10 = sm + ((size_t)(s1c * 128 + cx0) * 8) * 16;
        const char* r11 = sm + ((size_t)(s1c * 128 + cx1) * 8) * 16;

        bf16x8 a00 = *(const bf16x8*)(r00 + (((kb     + key0) & 7) << 4));
        bf16x8 c00 = *(const bf16x8*)(r00 + (((kb + 4 + key0) & 7) << 4));
        bf16x8 a01 = *(const bf16x8*)(r01 + (((kb     + key1) & 7) << 4));
        bf16x8 c01 = *(const bf16x8*)(r01 + (((kb + 4 + key1) & 7) << 4));
        bf16x8 a10 = *(const bf16x8*)(r10 + (((kb     + key0) & 7) << 4));
        bf16x8 c10 = *(const bf16x8*)(r10 + (((kb + 4 + key0) & 7) << 4));
        bf16x8 a11 = *(const bf16x8*)(r11 + (((kb     + key1) & 7) << 4));
        bf16x8 c11 = *(const bf16x8*)(r11 + (((kb + 4 + key1) & 7) << 4));

        // rare out-of-window fallback (exec-masked)
        if (__builtin_expect(need0, 0)) {
            const float* gl = xb + (size_t)(kb * 8) * HW_ + (size_t)cy0 * W_;
            const float* gh = gl + (size_t)32 * HW_;
#pragma unroll
            for (int e = 0; e < 8; ++e) {
                a00[e] = (__bf16)gl[(size_t)e * HW_ + cx0];
                a01[e] = (__bf16)gl[(size_t)e * HW_ + cx1];
                c00[e] = (__bf16)gh[(size_t)e * HW_ + cx0];
                c01[e] = (__bf16)gh[(size_t)e * HW_ + cx1];
            }
        }
        if (__builtin_expect(need1, 0)) {
            const float* gl = xb + (size_t)(kb * 8) * HW_ + (size_t)cy1 * W_;
            const float* gh = gl + (size_t)32 * HW_;
#pragma unroll
            for (int e = 0; e < 8; ++e) {
                a10[e] = (__bf16)gl[(size_t)e * HW_ + cx0];
                a11[e] = (__bf16)gl[(size_t)e * HW_ + cx1];
                c10[e] = (__bf16)gh[(size_t)e * HW_ + cx0];
                c11[e] = (__bf16)gh[(size_t)e * HW_ + cx1];
            }
        }

        if (k + 1 < K2_) {   // prefetch next tap's offsets
            oy = offb[(2 * (k + 1)) * HW_];
            ox = offb[(2 * (k + 1) + 1) * HW_];
            mm = mb[(k + 1) * HW_];
        }

        bf16x8 bf0, bf1;
#pragma unroll
        for (int e = 0; e < 8; ++e) {
            const float v0 = W00 * (float)a00[e] + W01 * (float)a01[e]
                           + W10 * (float)a10[e] + W11 * (float)a11[e];
            const float v1 = W00 * (float)c00[e] + W01 * (float)c01[e]
                           + W10 * (float)c10[e] + W11 * (float)c11[e];
            bf0[e] = (__bf16)v0;
            bf1[e] = (__bf16)v1;
        }

        const __bf16* wk = wt3 + (size_t)k * (2 * 4 * 64 * 8);
#pragma unroll
        for (int ct = 0; ct < 4; ++ct) {
            const bf16x8 A0 = *(const bf16x8*)(wk + (0 * 4 + ct) * 512 + lane * 8);
            const bf16x8 A1 = *(const bf16x8*)(wk + (1 * 4 + ct) * 512 + lane * 8);
            acc[ct] = __builtin_amdgcn_mfma_f32_16x16x32_bf16(A0, bf0, acc[ct], 0, 0, 0);
            acc[ct] = __builtin_amdgcn_mfma_f32_16x16x32_bf16(A1, bf1, acc[ct], 0, 0, 0);
        }
    }

    // ---------- epilogue: D col = n16 (px), row = kb*4 + r (+ ct*16) ----------
#pragma unroll
    for (int ct = 0; ct < 4; ++ct) {
#pragma unroll
        for (int r = 0; r < 4; ++r) {
            const int co = ct * 16 + kb * 4 + r;
            out[((size_t)(b * COUT_ + co)) * HW_ + pix] = acc[ct][r] + bias[co];
        }
    }
}

extern "C" void kernel_launch(void* const* d_in, const int* in_sizes, int n_in,
                              void* d_out, int out_size, void* d_ws, size_t ws_size,
                              hipStream_t stream) {
    const float* x      = (const float*)d_in[0];
    const float* offset = (const float*)d_in[1];
    const float* mask   = (const float*)d_in[2];
    const float* weight = (const float*)d_in[3];
    const float* bias   = (const float*)d_in[4];
    float* out = (float*)d_out;
    __bf16* wt3 = (__bf16*)d_ws;   // 73728 bytes

    // allow 163840 B dynamic LDS (gfx950 workgroup max is 160 KiB)
    hipFuncSetAttribute(reinterpret_cast<const void*>(dcn_lds_kernel),
                        hipFuncAttributeMaxDynamicSharedMemorySize, LDS_BYTES);

    wtrans3_kernel<<<(K2_ * 2 * 4 * 64 * 8 + 255) / 256, 256, 0, stream>>>(weight, wt3);
    // 256 blocks x 1024 threads: one block per CU, 2 output rows per block
    dcn_lds_kernel<<<B_ * H_ / 2, 1024, LDS_BYTES, stream>>>(x, offset, mask, wt3, bias, out);
}